// Round 4
// baseline (7468.772 us; speedup 1.0000x reference)
//
#include <hip/hip_runtime.h>

// ---------------------------------------------------------------------------
// UNet DeltaNet forward, MI355X/gfx950 — round 4.
// fp32 in/out; q/k/v/o/w/qk intermediates bf16; all accumulation fp32.
// Shapes: B=8, C=768, L=4096, n_heads=12, D=64, CHUNK=64, BH=96.
//
//  1) k_beta : beta = sigmoid(x^T @ Wb)                       (fp32)
//  2) k_proj : q/k = l2norm(silu(t@W)), v = silu(t@Wv) -> bf16 [b][h][l][d]
//  3) k_pre  : per (b,h,chunk) [6144 blocks]: MFMA KK^T/QK^T; As=strict(b*KK^T);
//              register forward-substitution -> u_pre (over v), w; masked qk.
//  4) k_seq  : per (b,h, e-group) [384 blocks]: sequential over 64 chunks:
//              U = u_pre - W*S; O = Q*S + qk*U -> o; S += K^T*U (S fp32 LDS)
//  5) k_final: out = x + (o @ Wo)^T                           (fp32 out)
// ---------------------------------------------------------------------------

#define B_  8
#define C_  768
#define L_  4096
#define NH_ 12
#define D_  64
#define NC_ 64
#define BH_ 96

typedef unsigned short ushort_t;
typedef float f32x4 __attribute__((ext_vector_type(4)));
typedef unsigned short u16x4 __attribute__((ext_vector_type(4)));
typedef unsigned short u16x8 __attribute__((ext_vector_type(8)));
typedef __bf16 bf16x8 __attribute__((ext_vector_type(8)));

__device__ __forceinline__ float b2f(ushort_t u) {
  union { unsigned u; float f; } x; x.u = ((unsigned)u) << 16; return x.f;
}
__device__ __forceinline__ ushort_t f2b(float f) {
  union { float f; unsigned u; } x; x.f = f;
  unsigned r = (x.u + 0x7FFFu + ((x.u >> 16) & 1u)) >> 16;
  return (ushort_t)r;
}

// ---------------------------------------------------------------------------
// beta = sigmoid(x^T @ Wb); grid (L/256, B), 256 thr.
__global__ __launch_bounds__(256) void k_beta(
    const float* __restrict__ x, const float* __restrict__ Wb,
    float* __restrict__ beta) {
  __shared__ float wb[C_ * NH_];   // 36 KB
  int tid = threadIdx.x;
  for (int i = tid; i < C_ * NH_; i += 256) wb[i] = Wb[i];
  __syncthreads();
  int b = blockIdx.y;
  int l = blockIdx.x * 256 + tid;
  f32x4 a0 = {0.f, 0.f, 0.f, 0.f}, a1 = a0, a2 = a0;
  const float* xb = x + (size_t)b * C_ * L_ + l;
  for (int c = 0; c < C_; ++c) {
    float xv = xb[(size_t)c * L_];
    const f32x4* wr = (const f32x4*)&wb[c * NH_];
    a0 += xv * wr[0]; a1 += xv * wr[1]; a2 += xv * wr[2];
  }
  float* bp = beta + (size_t)b * NH_ * L_ + l;
  #pragma unroll
  for (int h = 0; h < 4; ++h) {
    bp[(size_t)h * L_]       = 1.f / (1.f + expf(-a0[h]));
    bp[(size_t)(h + 4) * L_] = 1.f / (1.f + expf(-a1[h]));
    bp[(size_t)(h + 8) * L_] = 1.f / (1.f + expf(-a2[h]));
  }
}

// ---------------------------------------------------------------------------
// Projection GEMM: out[b][h][l][d] = epi( sum_c x[b][c][l] * W[c][h*64+d] )
// 128x64 C-tile, thread = 8x4. grid (L/128, NH, B), 256 thr. Output bf16.
__global__ __launch_bounds__(256) void k_proj(
    const float* __restrict__ x, const float* __restrict__ W,
    ushort_t* __restrict__ outp, int norm) {
  __shared__ float As[32 * 128];  // 16 KB  As[kk][row]
  __shared__ float Bs[32 * 64];   //  8 KB  Bs[kk][col]
  int tid = threadIdx.x;
  int b = blockIdx.z, h = blockIdx.y;
  int l0 = blockIdx.x * 128;
  int ti = tid >> 4, tj = tid & 15;
  float acc[8][4];
  #pragma unroll
  for (int r = 0; r < 8; ++r)
    #pragma unroll
    for (int s = 0; s < 4; ++s) acc[r][s] = 0.f;
  const float* xb = x + (size_t)b * C_ * L_ + l0;
  const float* wb = W + h * 64;
  for (int kb = 0; kb < C_; kb += 32) {
    #pragma unroll
    for (int it = 0; it < 4; ++it) {
      int e = tid + it * 256;          // 1024 f32x4
      int kk = e >> 5, lq = e & 31;
      *(f32x4*)&As[kk * 128 + lq * 4] =
          *(const f32x4*)(xb + (size_t)(kb + kk) * L_ + lq * 4);
    }
    #pragma unroll
    for (int it = 0; it < 2; ++it) {
      int e = tid + it * 256;          // 512 f32x4
      int kk = e >> 4, nq = e & 15;
      *(f32x4*)&Bs[kk * 64 + nq * 4] =
          *(const f32x4*)(wb + (size_t)(kb + kk) * C_ + nq * 4);
    }
    __syncthreads();
    #pragma unroll 8
    for (int kk = 0; kk < 32; ++kk) {
      f32x4 a0 = *(const f32x4*)&As[kk * 128 + ti * 8];
      f32x4 a1 = *(const f32x4*)&As[kk * 128 + ti * 8 + 4];
      f32x4 bv = *(const f32x4*)&Bs[kk * 64 + tj * 4];
      #pragma unroll
      for (int r = 0; r < 4; ++r)
        #pragma unroll
        for (int s = 0; s < 4; ++s) {
          acc[r][s]     += a0[r] * bv[s];
          acc[r + 4][s] += a1[r] * bv[s];
        }
    }
    __syncthreads();
  }
  #pragma unroll
  for (int r = 0; r < 8; ++r)
    #pragma unroll
    for (int s = 0; s < 4; ++s) {
      float xv = acc[r][s];
      acc[r][s] = xv / (1.f + expf(-xv));
    }
  if (norm) {
    #pragma unroll
    for (int r = 0; r < 8; ++r) {
      float ss = acc[r][0]*acc[r][0] + acc[r][1]*acc[r][1]
               + acc[r][2]*acc[r][2] + acc[r][3]*acc[r][3];
      ss += __shfl_xor(ss, 1); ss += __shfl_xor(ss, 2);
      ss += __shfl_xor(ss, 4); ss += __shfl_xor(ss, 8);
      float rs = rsqrtf(ss + 1e-6f);
      #pragma unroll
      for (int s = 0; s < 4; ++s) acc[r][s] *= rs;
    }
  }
  ushort_t* ob = outp + (((size_t)b * NH_ + h) * L_ + l0 + ti * 8) * 64 + tj * 4;
  #pragma unroll
  for (int r = 0; r < 8; ++r) {
    u16x4 pv = {f2b(acc[r][0]), f2b(acc[r][1]), f2b(acc[r][2]), f2b(acc[r][3])};
    *(u16x4*)(ob + (size_t)r * 64) = pv;
  }
}

// ---------------------------------------------------------------------------
// Per-chunk S-independent precompute. grid (NC, BH) = 6144 blocks, 256 thr.
// MFMA for KK^T and QK^T; register-resident forward substitution.
// Writes: qkM (incl-masked QK^T, bf16), wmat = T^-1(beta*K) (bf16),
//         upre = T^-1(beta*V) (bf16, in-place over v — column-disjoint).
__global__ __launch_bounds__(256) void k_pre(
    const ushort_t* __restrict__ kg, const ushort_t* __restrict__ qg,
    const ushort_t* __restrict__ vg, const float* __restrict__ betag,
    ushort_t* __restrict__ qkM, ushort_t* __restrict__ wmat,
    ushort_t* __restrict__ upre) {
  __shared__ ushort_t Ks[64 * 64];   // 8 KB
  __shared__ ushort_t Qs[64 * 64];   // 8 KB
  __shared__ float As[64 * 64];      // 16 KB  strict_tril(beta_i * KK^T)
  __shared__ float bet[64];
  int tid = threadIdx.x;
  int nc = blockIdx.x, bh = blockIdx.y;
  size_t cb = ((size_t)bh * L_ + (size_t)nc * 64) * 64;
  {
    const u16x8* ks = (const u16x8*)(kg + cb);
    const u16x8* qs = (const u16x8*)(qg + cb);
    u16x8* kd = (u16x8*)Ks; u16x8* qd = (u16x8*)Qs;
    for (int v = tid; v < 512; v += 256) { kd[v] = ks[v]; qd[v] = qs[v]; }
    if (tid < 64) bet[tid] = betag[(size_t)bh * L_ + (size_t)nc * 64 + tid];
  }
  __syncthreads();
  // ---- MFMA: kk = K K^T, qk = Q K^T (both 64x64, 4 waves x 16-row slabs)
  {
    int lane = tid & 63, w = tid >> 6;
    int lane15 = lane & 15, quad = lane >> 4;
    f32x4 akk[4], aqk[4];
    #pragma unroll
    for (int jt = 0; jt < 4; ++jt) {
      akk[jt] = (f32x4){0.f,0.f,0.f,0.f};
      aqk[jt] = (f32x4){0.f,0.f,0.f,0.f};
    }
    #pragma unroll
    for (int half = 0; half < 2; ++half) {
      bf16x8 ak = *(const bf16x8*)&Ks[(w * 16 + lane15) * 64 + half * 32 + quad * 8];
      bf16x8 aq = *(const bf16x8*)&Qs[(w * 16 + lane15) * 64 + half * 32 + quad * 8];
      #pragma unroll
      for (int jt = 0; jt < 4; ++jt) {
        bf16x8 bk = *(const bf16x8*)&Ks[(jt * 16 + lane15) * 64 + half * 32 + quad * 8];
        akk[jt] = __builtin_amdgcn_mfma_f32_16x16x32_bf16(ak, bk, akk[jt], 0, 0, 0);
        aqk[jt] = __builtin_amdgcn_mfma_f32_16x16x32_bf16(aq, bk, aqk[jt], 0, 0, 0);
      }
    }
    // C/D layout: col = lane&15, row = quad*4 + reg  [m89]
    ushort_t* qkb = qkM + ((size_t)bh * NC_ + nc) * 4096;
    #pragma unroll
    for (int jt = 0; jt < 4; ++jt) {
      #pragma unroll
      for (int r = 0; r < 4; ++r) {
        int i = w * 16 + quad * 4 + r;
        int j = jt * 16 + lane15;
        As[i * 64 + j] = (j < i) ? bet[i] * akk[jt][r] : 0.f;
        qkb[i * 64 + j] = f2b((j <= i) ? aqk[jt][r] : 0.f);
      }
    }
  }
  __syncthreads();
  // ---- forward substitution (I+As) X = [beta*V | beta*K], X in registers.
  if (tid < 128) {
    int col = tid;
    float x[64];
    if (col < 64) {
      const ushort_t* vcol = vg + cb;
      #pragma unroll
      for (int j = 0; j < 64; ++j) x[j] = bet[j] * b2f(vcol[j * 64 + col]);
    } else {
      int c2 = col - 64;
      #pragma unroll
      for (int j = 0; j < 64; ++j) x[j] = bet[j] * b2f(Ks[j * 64 + c2]);
    }
    #pragma unroll
    for (int i = 1; i < 64; ++i) {
      float xi = x[i];
      #pragma unroll
      for (int j = 0; j < i; ++j) xi -= As[i * 64 + j] * x[j];
      x[i] = xi;
    }
    if (col < 64) {
      ushort_t* ub = upre + cb;     // overwrites v; this thread owns column col
      #pragma unroll
      for (int i = 0; i < 64; ++i) ub[i * 64 + col] = f2b(x[i]);
    } else {
      ushort_t* wb2 = wmat + ((size_t)bh * NC_ + nc) * 4096;
      int c2 = col - 64;
      #pragma unroll
      for (int i = 0; i < 64; ++i) wb2[i * 64 + c2] = f2b(x[i]);
    }
  }
}

// ---------------------------------------------------------------------------
// Sequential chunk scan. grid (4 e-groups, BH) = 384 blocks, 256 thr.
// S[64][16] fp32 in LDS. bf16 tiles padded to stride 72 (bank conflicts).
#define TS_ 72
__global__ __launch_bounds__(256) void k_seq(
    const ushort_t* __restrict__ qp, const ushort_t* __restrict__ kp,
    const ushort_t* __restrict__ wmat, const ushort_t* __restrict__ qkM,
    const ushort_t* __restrict__ upre, ushort_t* __restrict__ op) {
  __shared__ float Ssm[64 * 16];       // 4 KB
  __shared__ float Usm[64 * 16];       // 4 KB
  __shared__ float Up[64 * 16];        // 4 KB
  __shared__ ushort_t Kc[64 * TS_];    // 9 KB
  __shared__ ushort_t Qc[64 * TS_];
  __shared__ ushort_t Wc[64 * TS_];
  __shared__ ushort_t Ac[64 * TS_];
  int tid = threadIdx.x;
  int eg = blockIdx.x, bh = blockIdx.y;
  int b = bh / NH_, h = bh % NH_;
  int e = tid & 15, ig = tid >> 4;
  for (int idx = tid; idx < 1024; idx += 256) Ssm[idx] = 0.f;
  __syncthreads();
  for (int nc = 0; nc < NC_; ++nc) {
    size_t cb = ((size_t)bh * L_ + (size_t)nc * 64) * 64;
    size_t mb = ((size_t)bh * NC_ + nc) * 4096;
    {
      const u16x8* ks = (const u16x8*)(kp + cb);
      const u16x8* qs = (const u16x8*)(qp + cb);
      const u16x8* wsrc = (const u16x8*)(wmat + mb);
      const u16x8* asrc = (const u16x8*)(qkM + mb);
      for (int v = tid; v < 512; v += 256) {
        int i = v >> 3, o8 = (v & 7) * 8;
        *(u16x8*)&Kc[i * TS_ + o8] = ks[v];
        *(u16x8*)&Qc[i * TS_ + o8] = qs[v];
        *(u16x8*)&Wc[i * TS_ + o8] = wsrc[v];
        *(u16x8*)&Ac[i * TS_ + o8] = asrc[v];
      }
      const ushort_t* ub = upre + cb + eg * 16;
      for (int idx = tid; idx < 1024; idx += 256) {
        int i = idx >> 4, ee = idx & 15;
        Up[idx] = b2f(ub[(size_t)i * 64 + ee]);
      }
    }
    __syncthreads();
    // U = u_pre - W*S
    float u[4];
    #pragma unroll
    for (int r = 0; r < 4; ++r) u[r] = Up[(ig * 4 + r) * 16 + e];
    for (int d = 0; d < 64; d += 4) {
      float sv[4];
      #pragma unroll
      for (int q = 0; q < 4; ++q) sv[q] = Ssm[(d + q) * 16 + e];
      #pragma unroll
      for (int r = 0; r < 4; ++r) {
        u16x4 wv = *(const u16x4*)&Wc[(ig * 4 + r) * TS_ + d];
        u[r] -= b2f(wv[0])*sv[0] + b2f(wv[1])*sv[1] + b2f(wv[2])*sv[2] + b2f(wv[3])*sv[3];
      }
    }
    #pragma unroll
    for (int r = 0; r < 4; ++r) Usm[(ig * 4 + r) * 16 + e] = u[r];
    __syncthreads();
    // O = Q*S + qk*U  -> global o[b][l][c] (bf16)
    float o[4] = {0.f, 0.f, 0.f, 0.f};
    for (int d = 0; d < 64; d += 4) {
      float sv[4];
      #pragma unroll
      for (int q = 0; q < 4; ++q) sv[q] = Ssm[(d + q) * 16 + e];
      #pragma unroll
      for (int r = 0; r < 4; ++r) {
        u16x4 qv = *(const u16x4*)&Qc[(ig * 4 + r) * TS_ + d];
        o[r] += b2f(qv[0])*sv[0] + b2f(qv[1])*sv[1] + b2f(qv[2])*sv[2] + b2f(qv[3])*sv[3];
      }
    }
    for (int j = 0; j < 64; j += 4) {
      float uv[4];
      #pragma unroll
      for (int q = 0; q < 4; ++q) uv[q] = Usm[(j + q) * 16 + e];
      #pragma unroll
      for (int r = 0; r < 4; ++r) {
        u16x4 av = *(const u16x4*)&Ac[(ig * 4 + r) * TS_ + j];
        o[r] += b2f(av[0])*uv[0] + b2f(av[1])*uv[1] + b2f(av[2])*uv[2] + b2f(av[3])*uv[3];
      }
    }
    {
      ushort_t* ob = op + ((size_t)b * L_ + (size_t)nc * 64) * C_
                   + (size_t)h * 64 + eg * 16 + e;
      #pragma unroll
      for (int r = 0; r < 4; ++r) ob[(size_t)(ig * 4 + r) * C_] = f2b(o[r]);
    }
    __syncthreads();
    // S += K^T * U
    {
      float s4[4];
      #pragma unroll
      for (int r = 0; r < 4; ++r) s4[r] = Ssm[(ig * 4 + r) * 16 + e];
      for (int i = 0; i < 64; ++i) {
        float uv = Usm[i * 16 + e];
        u16x4 kv = *(const u16x4*)&Kc[i * TS_ + ig * 4];
        #pragma unroll
        for (int r = 0; r < 4; ++r) s4[r] += b2f(kv[r]) * uv;
      }
      #pragma unroll
      for (int r = 0; r < 4; ++r) Ssm[(ig * 4 + r) * 16 + e] = s4[r];
    }
    __syncthreads();
  }
}

// ---------------------------------------------------------------------------
// Final GEMM + residual: out[b][c][l] = x[b][c][l] + sum_k o[b][l][k]*Wo[k][c]
// o bf16 [b][l][c]; out fp32. grid (L/128, C/64, B), 256 thr.
__global__ __launch_bounds__(256) void k_final(
    const ushort_t* __restrict__ o, const float* __restrict__ Wo,
    const float* __restrict__ x, float* __restrict__ outp) {
  __shared__ float As[32 * 132];
  __shared__ float Bs[32 * 64];
  int tid = threadIdx.x;
  int b = blockIdx.z;
  int n0 = blockIdx.y * 64;
  int l0 = blockIdx.x * 128;
  int ti = tid >> 4, tj = tid & 15;
  float acc[8][4];
  #pragma unroll
  for (int r = 0; r < 8; ++r)
    #pragma unroll
    for (int s = 0; s < 4; ++s) acc[r][s] = 0.f;
  const ushort_t* obase = o + ((size_t)b * L_ + l0) * C_;
  const float* wb = Wo + n0;
  for (int kb = 0; kb < C_; kb += 32) {
    #pragma unroll
    for (int it = 0; it < 4; ++it) {
      int e = tid + it * 256;
      int row = e >> 3, c4 = e & 7;
      u16x4 lv = *(const u16x4*)(obase + (size_t)row * C_ + kb + c4 * 4);
      #pragma unroll
      for (int q = 0; q < 4; ++q) As[(c4 * 4 + q) * 132 + row] = b2f(lv[q]);
    }
    #pragma unroll
    for (int it = 0; it < 2; ++it) {
      int e = tid + it * 256;
      int kk = e >> 4, nq = e & 15;
      *(f32x4*)&Bs[kk * 64 + nq * 4] =
          *(const f32x4*)(wb + (size_t)(kb + kk) * C_ + nq * 4);
    }
    __syncthreads();
    #pragma unroll 8
    for (int kk = 0; kk < 32; ++kk) {
      f32x4 a0 = *(const f32x4*)&As[kk * 132 + ti * 8];
      f32x4 a1 = *(const f32x4*)&As[kk * 132 + ti * 8 + 4];
      f32x4 bv = *(const f32x4*)&Bs[kk * 64 + tj * 4];
      #pragma unroll
      for (int r = 0; r < 4; ++r)
        #pragma unroll
        for (int s = 0; s < 4; ++s) {
          acc[r][s]     += a0[r] * bv[s];
          acc[r + 4][s] += a1[r] * bv[s];
        }
    }
    __syncthreads();
  }
  #pragma unroll
  for (int s = 0; s < 4; ++s) {
    int n = n0 + tj * 4 + s;
    size_t base = ((size_t)b * C_ + n) * L_ + l0 + ti * 8;
    f32x4 xlo = *(const f32x4*)(x + base);
    f32x4 xhi = *(const f32x4*)(x + base + 4);
    f32x4 lo = {acc[0][s] + xlo[0], acc[1][s] + xlo[1],
                acc[2][s] + xlo[2], acc[3][s] + xlo[3]};
    f32x4 hi = {acc[4][s] + xhi[0], acc[5][s] + xhi[1],
                acc[6][s] + xhi[2], acc[7][s] + xhi[3]};
    *(f32x4*)(outp + base) = lo;
    *(f32x4*)(outp + base + 4) = hi;
  }
}

// ---------------------------------------------------------------------------
extern "C" void kernel_launch(void* const* d_in, const int* in_sizes, int n_in,
                              void* d_out, int out_size, void* d_ws, size_t ws_size,
                              hipStream_t stream) {
  (void)in_sizes; (void)n_in; (void)out_size; (void)ws_size;
  const float* x  = (const float*)d_in[0];
  const float* Wq = (const float*)d_in[1];
  const float* Wk = (const float*)d_in[2];
  const float* Wv = (const float*)d_in[3];
  const float* Wb = (const float*)d_in[4];
  const float* Wo = (const float*)d_in[5];
  float* outp = (float*)d_out;

  const size_t NE = (size_t)B_ * NH_ * L_ * D_;   // 25,165,824 elements
  ushort_t* q    = (ushort_t*)d_ws;               // bf16, 50.3 MB
  ushort_t* kbuf = q + NE;                        // bf16
  ushort_t* v    = kbuf + NE;                     // bf16; becomes u_pre
  float*    beta = (float*)(v + NE);              // fp32, 1.6 MB
  ushort_t* o    = (ushort_t*)(beta + (size_t)B_ * NH_ * L_);  // bf16 [B][L][C]
  ushort_t* qkM  = o + NE;                        // bf16, 50.3 MB
  ushort_t* wmat = qkM + NE;                      // bf16, 50.3 MB
  // total ws use ~303.6 MB (round-1 ran fine at 308.6 MB)

  k_beta<<<dim3(L_ / 256, B_), 256, 0, stream>>>(x, Wb, beta);
  k_proj<<<dim3(L_ / 128, NH_, B_), 256, 0, stream>>>(x, Wq, q, 1);
  k_proj<<<dim3(L_ / 128, NH_, B_), 256, 0, stream>>>(x, Wk, kbuf, 1);
  k_proj<<<dim3(L_ / 128, NH_, B_), 256, 0, stream>>>(x, Wv, v, 0);
  k_pre<<<dim3(NC_, BH_), 256, 0, stream>>>(kbuf, q, v, beta, qkM, wmat, v);
  k_seq<<<dim3(4, BH_), 256, 0, stream>>>(q, kbuf, wmat, qkM, v, o);
  k_final<<<dim3(L_ / 128, C_ / 64, B_), 256, 0, stream>>>(o, Wo, x, outp);
}